// Round 5
// baseline (162.532 us; speedup 1.0000x reference)
//
#include <hip/hip_runtime.h>

#define BIG 1e8f
#define LN2 0.69314718f
// band quantization: q = round(dist * QENC), dist_log2 = q * DDEC
#define QENC 1.7686573f   /* log2(e) * 255/208 */
#define DDEC 0.81568627f  /* 208/255 (log2 units) */

#define BROW 260          /* band row stride, bytes (+4 pad: conflict-free) */
#define SENTH 0x7F800000u /* +inf bits: never a real DP value */
#define SENT64 0x7F8000007F800000ULL

// LDS layout (dynamic, 91136 B total)
#define OFF_XH   66560    /* band: [0, 66560) = 256 rows * 260 */
#define OFF_X2S  82944    /* xh:   16384 B f16 */
#define OFF_Y2S  83968
#define OFF_MBOX 84992    /* 4 waves * 192 slots * 8 B = 6144 */
#define LDS_BYTES 91136

typedef _Float16 half8 __attribute__((ext_vector_type(8)));
typedef float f32x4 __attribute__((ext_vector_type(4)));

__device__ __forceinline__ float exp2g(float x) {
#if __has_builtin(__builtin_amdgcn_exp2f)
    return __builtin_amdgcn_exp2f(x);
#else
    return exp2f(x);
#endif
}
__device__ __forceinline__ float log2g(float x) {
#if __has_builtin(__builtin_amdgcn_logf)
    return __builtin_amdgcn_logf(x);
#else
    return log2f(x);
#endif
}

// pair precompute: m = min(a,b), s = 2^(m-a) + 2^(m-b) = 1 + 2^(-|a-b|)
__device__ __forceinline__ void pairp(float a, float b, float& m, float& s) {
    m = fminf(a, b);
    s = exp2g(-fabsf(a - b)) + 1.f;
}
// softmin of {pair (m,s), v}
__device__ __forceinline__ float smp(float m, float s, float v) {
    float d = v - m;
    float t = exp2g(-fabsf(d));
    float r = (d > 0.f) ? (t + s) : fmaf(s, t, 1.f);
    return fminf(m, v) - log2g(r);
}

// whole-wave shift-up-by-1 via DPP wave_shr:1; lane 0 receives oldv.
__device__ __forceinline__ float shfl_up1(float v, float oldv) {
    int r = __builtin_amdgcn_update_dpp(
        __builtin_bit_cast(int, oldv), __builtin_bit_cast(int, v),
        0x138 /*wave_shr:1*/, 0xf, 0xf, false);
    return __builtin_bit_cast(float, r);
}

__device__ __forceinline__ unsigned long long mread(const unsigned long long* p) {
    return *(volatile const unsigned long long*)p;
}

__device__ __forceinline__ unsigned int pack_d(f32x4 acc, float xx, float4 yy) {
    float dv;
    unsigned int pk;
    dv = fminf(fmaxf(fmaf(-2.f, acc[0], xx + yy.x), 0.f) * QENC, 254.9f);
    pk = (unsigned int)(dv + 0.5f);
    dv = fminf(fmaxf(fmaf(-2.f, acc[1], xx + yy.y), 0.f) * QENC, 254.9f);
    pk |= (unsigned int)(dv + 0.5f) << 8;
    dv = fminf(fmaxf(fmaf(-2.f, acc[2], xx + yy.z), 0.f) * QENC, 254.9f);
    pk |= (unsigned int)(dv + 0.5f) << 16;
    dv = fminf(fmaxf(fmaf(-2.f, acc[3], xx + yy.w), 0.f) * QENC, 254.9f);
    pk |= (unsigned int)(dv + 0.5f) << 24;
    return pk;
}

// One block = one batch, 4 waves. Wave w owns columns 64w..64w+63 (0-based),
// lane g = tid owns column g. 2-row supersteps: at global superstep s, lane g
// computes rows rA=2(s-g)-1, rB=2(s-g). Wave w executes only its active
// window s in [64w+1, 64w+192] (192 iterations). In-wave relay via DPP;
// wave boundary via write-once LDS mailbox (sentinel-flagged u64, 1-superstep
// skew: wave w at it reads wave w-1's slot it+63). Full 256x256 u8 distance
// matrix precomputed into LDS by MFMA in phase 1 (4 waves x 4 col-tiles).
__global__ __launch_bounds__(256, 1) void sdtw_kernel(
    const float* __restrict__ x, const float* __restrict__ y,
    float* __restrict__ out) {
    extern __shared__ __align__(16) char smem[];
    unsigned char* band = (unsigned char*)smem;
    _Float16* xh = (_Float16*)(smem + OFF_XH);
    float* x2s = (float*)(smem + OFF_X2S);
    float* y2s = (float*)(smem + OFF_Y2S);
    unsigned long long* mbox = (unsigned long long*)(smem + OFF_MBOX);

    const int tid = threadIdx.x;   // 0..255
    const int W = tid >> 6;        // wave id 0..3
    const int lane = tid & 63;
    const int g = tid;             // global 0-based column
    const int b = blockIdx.x;
    const float* xb = x + (size_t)b * 8192;
    const float* yb = y + (size_t)b * 8192;

    // ---- phase 0: stage x as f16 + norms (1 row/thread); y norms; mbox init
    {
        const int r = tid;
        const float4* px = (const float4*)(xb + r * 32);
        union { _Float16 h[32]; half8 v[4]; } uc;
        float s2 = 0.f;
#pragma unroll
        for (int q = 0; q < 8; q++) {
            float4 f = px[q];
            s2 += f.x * f.x + f.y * f.y + f.z * f.z + f.w * f.w;
            uc.h[4 * q + 0] = (_Float16)f.x;
            uc.h[4 * q + 1] = (_Float16)f.y;
            uc.h[4 * q + 2] = (_Float16)f.z;
            uc.h[4 * q + 3] = (_Float16)f.w;
        }
        half8* dst = (half8*)&xh[r * 32];
#pragma unroll
        for (int q = 0; q < 4; q++) dst[q] = uc.v[q];
        x2s[r] = s2;

        const float4* py = (const float4*)(yb + r * 32);
        float t2 = 0.f;
#pragma unroll
        for (int q = 0; q < 8; q++) {
            float4 f = py[q];
            t2 += f.x * f.x + f.y * f.y + f.z * f.z + f.w * f.w;
        }
        y2s[r] = t2;

        for (int i = tid; i < 4 * 192; i += 256) mbox[i] = SENT64;
    }
    __syncthreads();

    // ---- phase 1: full 256x256 u8 distance matrix via MFMA ----
    // Wave w produces col-tiles ci = 4w..4w+3 for all 16 row-stripes.
    // Transposed product: A = y-tile frag, B = x-stripe frag; lane holds
    // D[ycol = qd*4+reg][xrow = lane&15] -> one packed u32 write per tile.
    {
        half8 yf[4];  // static-indexed only
#pragma unroll
        for (int j = 0; j < 4; j++) {
            const int ci = 4 * W + j;
            const float* yp = yb + (ci * 16 + (lane & 15)) * 32 + (lane >> 4) * 8;
            float4 f0 = *(const float4*)yp;
            float4 f1 = *(const float4*)(yp + 4);
            half8 v;
            v[0] = (_Float16)f0.x; v[1] = (_Float16)f0.y;
            v[2] = (_Float16)f0.z; v[3] = (_Float16)f0.w;
            v[4] = (_Float16)f1.x; v[5] = (_Float16)f1.y;
            v[6] = (_Float16)f1.z; v[7] = (_Float16)f1.w;
            yf[j] = v;
        }
        const int qd = lane >> 4, xr = lane & 15;
        for (int sg = 0; sg < 16; sg++) {
            const half8 bf = *(const half8*)&xh[(sg * 16 + xr) * 32 + qd * 8];
            const float xx = x2s[sg * 16 + xr];
            unsigned char* rowp = &band[(sg * 16 + xr) * BROW];
#pragma unroll
            for (int j = 0; j < 4; j++) {
                const int ci = 4 * W + j;
                f32x4 acc = {0.f, 0.f, 0.f, 0.f};
                acc = __builtin_amdgcn_mfma_f32_16x16x32_f16(yf[j], bf, acc, 0, 0, 0);
                const float4 yy = *(const float4*)&y2s[ci * 16 + qd * 4];
                *(unsigned int*)&rowp[ci * 16 + qd * 4] = pack_d(acc, xx, yy);
            }
        }
    }
    __syncthreads();

    // ---- phase 2: DP wavefront, per-wave window of 192 supersteps ----
    float u = BIG, pA = BIG, pB = BIG;
    float G0 = (g == 0) ? 0.f : BIG;  // D[rA-1][c-1] seed
    float m0p, s0p;
    pairp(u, G0, m0p, s0p);           // pair(up=u, diag=G0) for first superstep

    const int s_start = 64 * W + 1;
    int r0 = 2 * s_start - 2 * g - 2;             // 0-based row of A-cell
    r0 = r0 < 0 ? 0 : (r0 > 254 ? 254 : r0);
    unsigned char ua = band[r0 * BROW + g];
    unsigned char ub = band[(r0 + 1) * BROW + g];
    unsigned long long mval = (W > 0) ? mread(&mbox[(W - 1) * 192 + 63]) : 0ULL;

#pragma unroll 4
    for (int it = 0; it < 192; it++) {
        const int s = s_start + it;

        float L0 = shfl_up1(pA, BIG);  // D[rA][c-1]
        float L1 = shfl_up1(pB, BIG);  // D[rB][c-1]
        if (W > 0 && it < 128) {       // wave-uniform; lane0 active window
            unsigned long long m = mval;
            while ((unsigned)(m >> 32) == SENTH || (unsigned)m == SENTH)
                m = mread(&mbox[(W - 1) * 192 + it + 63]);
            if (lane == 0) {
                L0 = __uint_as_float((unsigned)m);
                L1 = __uint_as_float((unsigned)(m >> 32));
            }
            if (it < 127) mval = mread(&mbox[(W - 1) * 192 + it + 64]);
        }

        const float dA = (float)ua * DDEC;
        const float dB = (float)ub * DDEC;

        // A-cell: softmin(up=u, left=L0, diag=G0); pair (m0p,s0p) precomputed
        const float A = dA + smp(m0p, s0p, L0);

        // band prefetch for next superstep (off-chain)
        int rn = 2 * (s + 1) - 2 * g - 2;
        rn = rn < 0 ? 0 : (rn > 254 ? 254 : rn);
        const unsigned char uan = band[rn * BROW + g];
        const unsigned char ubn = band[(rn + 1) * BROW + g];

        // B-cell: softmin(up=A, left=L1, diag=L0)
        float n0, t0;
        pairp(A, L0, n0, t0);
        const float B = dB + smp(n0, t0, L1);

        // publish boundary values for wave W+1 (write-once slot; single b64)
        if (lane == 63)
            *(volatile unsigned long long*)&mbox[W * 192 + it] =
                ((unsigned long long)__float_as_uint(B) << 32) | __float_as_uint(A);

        // state update
        const int rA = 2 * (s - g) - 1;
        const bool act = (rA >= 1) && (rA <= 255);
        u = act ? B : u;
        pA = act ? A : pA;
        pB = act ? B : pB;
        G0 = L1;                       // diag(s+1) = D[rB(s)][c-1]
        pairp(u, G0, m0p, s0p);        // pair for next superstep (off-chain)
        ua = uan;
        ub = ubn;
    }

    if (tid == 255) atomicAdd(out, u * (LN2 / 256.f));  // D[256][256] -> mean
}

extern "C" void kernel_launch(void* const* d_in, const int* in_sizes, int n_in,
                              void* d_out, int out_size, void* d_ws, size_t ws_size,
                              hipStream_t stream) {
    const float* x = (const float*)d_in[0];
    const float* y = (const float*)d_in[1];
    float* out = (float*)d_out;
    const int B = in_sizes[0] / (256 * 32);  // 256

    hipFuncSetAttribute((const void*)sdtw_kernel,
                        hipFuncAttributeMaxDynamicSharedMemorySize, LDS_BYTES);
    hipMemsetAsync(d_out, 0, sizeof(float), stream);
    sdtw_kernel<<<dim3(B), dim3(256), LDS_BYTES, stream>>>(x, y, out);
}

// Round 7
// 136.705 us; speedup vs baseline: 1.1889x; 1.1889x over previous
//
#include <hip/hip_runtime.h>

#define BIG 1e8f
#define LN2 0.69314718f
#define LOG2E 1.44269504f
#define M2L -2.8853900818f  /* -2*log2(e) */

#define RSLOT 112           /* band ring slots (anti-diagonal rows) */
#define DRB 1040            /* drow stride bytes: 256 cols * 4B(half2) + 16 pad */

/* dynamic LDS layout */
#define OFF_XH   116480     /* band: [0, 116480) = 112*1040 */
#define OFF_X2S  132864     /* xh: 16384 B f16 */
#define OFF_Y2S  133888
#define OFF_RDY  134912     /* 16 ready flags */
#define OFF_PRG  134976     /* consumer progress */
#define LDS_BYTES 135040

typedef _Float16 half8 __attribute__((ext_vector_type(8)));
typedef _Float16 half2_t __attribute__((ext_vector_type(2)));
typedef float f32x4 __attribute__((ext_vector_type(4)));

__device__ __forceinline__ float exp2g(float x) {
#if __has_builtin(__builtin_amdgcn_exp2f)
    return __builtin_amdgcn_exp2f(x);
#else
    return exp2f(x);
#endif
}
__device__ __forceinline__ float log2g(float x) {
#if __has_builtin(__builtin_amdgcn_logf)
    return __builtin_amdgcn_logf(x);
#else
    return log2f(x);
#endif
}

// pack two f32 to f16x2 (v_cvt_pkrtz_f16_f32); bit_cast fixes the __fp16
// vs _Float16 vector-type mismatch of the raw builtin's return type.
__device__ __forceinline__ half2_t pkrtz(float a, float b) {
    return __builtin_bit_cast(half2_t, __builtin_amdgcn_cvt_pkrtz(a, b));
}

// pair precompute: m = min(a,b), s = 2^(m-a)+2^(m-b) = 1 + 2^(-|a-b|)
__device__ __forceinline__ void pairp(float a, float b, float& m, float& s) {
    m = fminf(a, b);
    s = exp2g(-fabsf(a - b)) + 1.f;
}
// softmin of {pair (m,s), v}
__device__ __forceinline__ float smp(float m, float s, float v) {
    float d = v - m;
    float t = exp2g(-fabsf(d));
    float r = (d > 0.f) ? (t + s) : fmaf(s, t, 1.f);
    return fminf(m, v) - log2g(r);
}

// whole-wave shift-up-by-1 via DPP wave_shr:1; lane 0 receives oldv.
__device__ __forceinline__ float shfl_up1(float v, float oldv) {
    int r = __builtin_amdgcn_update_dpp(
        __builtin_bit_cast(int, oldv), __builtin_bit_cast(int, v),
        0x138 /*wave_shr:1*/, 0xf, 0xf, false);
    return __builtin_bit_cast(float, r);
}

__device__ __forceinline__ void dec2(unsigned int w, float& a, float& b) {
    half2_t h = __builtin_bit_cast(half2_t, w);
    a = (float)h[0];
    b = (float)h[1];
}

// One block = one batch, 2 waves on 2 SIMDs.
// Wave 1 (producer): MFMA-computes dist*log2(e) as f16 (dA,dB) pairs into an
//   anti-diagonal-major LDS ring (drow d holds, for each lane-group g, the
//   cell pair p=d-g of cols 4g..4g+3). Runs flat out, gated by a coarse
//   consumer-progress counter; sets ready[stripe] after each 16-row stripe.
// Wave 0 (consumer): R4-verified DP wavefront, lane g owns cols 4g+1..4g+4,
//   2-row supersteps s=1..191. Per superstep: ONE conflict-free contiguous
//   ds_read_b128 (drow s-1 is the same row for all lanes), DPP relay, 8
//   softmins. Ready-flag poll only once per 8 supersteps (slack-rich).
__global__ __launch_bounds__(128, 1) void sdtw_kernel(
    const float* __restrict__ x, const float* __restrict__ y,
    float* __restrict__ out) {
    extern __shared__ __align__(16) char smem[];
    unsigned char* band = (unsigned char*)smem;
    _Float16* xh = (_Float16*)(smem + OFF_XH);
    float* x2sL = (float*)(smem + OFF_X2S);   // row norms * log2(e)
    float* y2sL = (float*)(smem + OFF_Y2S);
    volatile int* rdy = (volatile int*)(smem + OFF_RDY);
    volatile int* prg = (volatile int*)(smem + OFF_PRG);

    const int tid = threadIdx.x;  // 0..127
    const int b = blockIdx.x;
    const float* xb = x + (size_t)b * 8192;
    const float* yb = y + (size_t)b * 8192;

    // ---- phase 0 (both waves): stage x as f16 + scaled norms; flags ----
#pragma unroll
    for (int rr = 0; rr < 2; rr++) {
        const int r = tid + rr * 128;
        const float4* px = (const float4*)(xb + r * 32);
        union { _Float16 h[32]; half8 v[4]; } uc;
        float s2 = 0.f;
#pragma unroll
        for (int q = 0; q < 8; q++) {
            float4 f = px[q];
            s2 += f.x * f.x + f.y * f.y + f.z * f.z + f.w * f.w;
            uc.h[4 * q + 0] = (_Float16)f.x;
            uc.h[4 * q + 1] = (_Float16)f.y;
            uc.h[4 * q + 2] = (_Float16)f.z;
            uc.h[4 * q + 3] = (_Float16)f.w;
        }
        half8* dst = (half8*)&xh[r * 32];
#pragma unroll
        for (int q = 0; q < 4; q++) dst[q] = uc.v[q];
        x2sL[r] = s2 * LOG2E;

        const float4* py = (const float4*)(yb + r * 32);
        float t2 = 0.f;
#pragma unroll
        for (int q = 0; q < 8; q++) {
            float4 f = py[q];
            t2 += f.x * f.x + f.y * f.y + f.z * f.z + f.w * f.w;
        }
        y2sL[r] = t2 * LOG2E;
    }
    if (tid < 16) rdy[tid] = 0;
    if (tid == 16) *prg = 0;
    __syncthreads();

    if (tid >= 64) {
        // ================= producer wave =================
        const int lane = tid - 64;
        const int qd = lane >> 4, xr = lane & 15;

        half8 yfrag[16];  // B-frags: lane holds y[ci*16+xr][qd*8+j]
        float yvL[16];
#pragma unroll
        for (int ci = 0; ci < 16; ci++) {
            const float* yp = yb + (ci * 16 + xr) * 32 + qd * 8;
            float4 f0 = *(const float4*)yp;
            float4 f1 = *(const float4*)(yp + 4);
            half8 v;
            v[0] = (_Float16)f0.x; v[1] = (_Float16)f0.y;
            v[2] = (_Float16)f0.z; v[3] = (_Float16)f0.w;
            v[4] = (_Float16)f1.x; v[5] = (_Float16)f1.y;
            v[6] = (_Float16)f1.z; v[7] = (_Float16)f1.w;
            yfrag[ci] = v;
            yvL[ci] = y2sL[ci * 16 + xr];
        }

        for (int sg = 0; sg < 16; sg++) {
            // ring-reuse gate: stripe sg touches drows [8sg, 8sg+70]; the
            // aliased drows (d-112) need consumer progress >= 8sg-40.
            if (sg >= 6) {
                const int need = 8 * sg - 40;
                while (*prg < need) {}
            }
            const half8 xf = *(const half8*)&xh[(sg * 16 + xr) * 32 + qd * 8];
            const float4 xl = *(const float4*)&x2sL[sg * 16 + qd * 4];
            const int p0 = 8 * sg + 2 * qd;  // global pair of acc[0],acc[1]
#pragma unroll
            for (int ci = 0; ci < 16; ci++) {
                f32x4 acc = {0.f, 0.f, 0.f, 0.f};
                acc = __builtin_amdgcn_mfma_f32_16x16x32_f16(xf, yfrag[ci], acc, 0, 0, 0);
                const int c = ci * 16 + xr;
                const float yv = yvL[ci];
                const float d0 = fmaxf(fmaf(M2L, acc[0], xl.x + yv), 0.f);
                const float d1 = fmaxf(fmaf(M2L, acc[1], xl.y + yv), 0.f);
                const float d2 = fmaxf(fmaf(M2L, acc[2], xl.z + yv), 0.f);
                const float d3 = fmaxf(fmaf(M2L, acc[3], xl.w + yv), 0.f);
                const half2_t h01 = pkrtz(d0, d1);
                const half2_t h23 = pkrtz(d2, d3);
                const int dr0 = p0 + (c >> 2);          // anti-diagonal row
                int s0_ = dr0;     if (s0_ >= RSLOT) s0_ -= RSLOT;
                int s1_ = dr0 + 1; if (s1_ >= RSLOT) s1_ -= RSLOT;
                *(half2_t*)&band[s0_ * DRB + 4 * c] = h01;
                *(half2_t*)&band[s1_ * DRB + 4 * c] = h23;
            }
            __threadfence_block();  // drain LDS writes before flagging
            if (lane == 0) rdy[sg] = 1;
        }
        return;
    }

    // ================= consumer (DP) wave =================
    const int lane = tid;
    float u0 = BIG, u1 = BIG, u2 = BIG, u3 = BIG, pA3 = BIG, pB3 = BIG;
    float G0 = (lane == 0) ? 0.f : BIG;
    float m0, s0, m1, s1, m2, s2, m3, s3;
    pairp(u0, G0, m0, s0);
    pairp(u1, u0, m1, s1);
    pairp(u2, u1, m2, s2);
    pairp(u3, u2, m3, s3);

    while (rdy[0] == 0) {}
    uint4 wreg = *(const uint4*)&band[16 * lane];  // drow 0

    for (int s_ = 1; s_ <= 191; s_++) {
        // chain head: pure-VALU cross-lane relay
        const float L0 = shfl_up1(pA3, BIG);  // D[rA][c-1]
        const float L1 = shfl_up1(pB3, BIG);  // D[rB][c-1]

        float dA0, dB0, dA1, dB1, dA2, dB2, dA3, dB3;
        dec2(wreg.x, dA0, dB0);
        dec2(wreg.y, dA1, dB1);
        dec2(wreg.z, dA2, dB2);
        dec2(wreg.w, dA3, dB3);

        // A-row chain (pairs m*,s* precomputed last superstep)
        const float A0 = dA0 + smp(m0, s0, L0);
        const float A1 = dA1 + smp(m1, s1, A0);
        const float A2 = dA2 + smp(m2, s2, A1);
        const float A3 = dA3 + smp(m3, s3, A2);

        // once per 8 supersteps: stripe-ready poll + progress publish
        if ((s_ & 7) == 0) {
            int st = s_ >> 3;
            if (st > 15) st = 15;
            while (rdy[st] == 0) {}
            if (lane == 0) *prg = s_;
        }
        // prefetch next drow (= s_), used next superstep
        int dn = (s_ > 190) ? 190 : s_;
        if (dn >= RSLOT) dn -= RSLOT;
        const uint4 wnext = *(const uint4*)&band[dn * DRB + 16 * lane];

        // B-row pairs + chain
        float n0, t0, n1, t1, n2, t2, n3, t3;
        pairp(A0, L0, n0, t0);
        pairp(A1, A0, n1, t1);
        pairp(A2, A1, n2, t2);
        pairp(A3, A2, n3, t3);
        const float B0 = dB0 + smp(n0, t0, L1);
        const float B1 = dB1 + smp(n1, t1, B0);
        const float B2 = dB2 + smp(n2, t2, B1);
        const float B3 = dB3 + smp(n3, t3, B2);

        // commit (lane active iff pair p = s_-lane-1 in [0,127])
        const bool act = (unsigned)(s_ - lane - 1) < 128u;
        u0 = act ? B0 : u0;
        u1 = act ? B1 : u1;
        u2 = act ? B2 : u2;
        u3 = act ? B3 : u3;
        pA3 = act ? A3 : pA3;
        pB3 = act ? B3 : pB3;
        G0 = L1;  // diag(s+1) = D[rB(s)][c-1]
        pairp(u0, G0, m0, s0);
        pairp(u1, u0, m1, s1);
        pairp(u2, u1, m2, s2);
        pairp(u3, u2, m3, s3);
        wreg = wnext;
    }

    if (lane == 63) atomicAdd(out, u3 * (LN2 / 256.f));  // D[256][256] -> mean
}

extern "C" void kernel_launch(void* const* d_in, const int* in_sizes, int n_in,
                              void* d_out, int out_size, void* d_ws, size_t ws_size,
                              hipStream_t stream) {
    const float* x = (const float*)d_in[0];
    const float* y = (const float*)d_in[1];
    float* out = (float*)d_out;
    const int B = in_sizes[0] / (256 * 32);  // 256

    (void)hipFuncSetAttribute((const void*)sdtw_kernel,
                              hipFuncAttributeMaxDynamicSharedMemorySize,
                              LDS_BYTES);
    (void)hipMemsetAsync(d_out, 0, sizeof(float), stream);
    sdtw_kernel<<<dim3(B), dim3(128), LDS_BYTES, stream>>>(x, y, out);
}